// Round 17
// baseline (184.661 us; speedup 1.0000x reference)
//
#include <hip/hip_runtime.h>
#include <hip/hip_bf16.h>
#include <stdint.h>

typedef _Float16 f16;
typedef __attribute__((ext_vector_type(8))) _Float16 f16x8;
typedef __attribute__((ext_vector_type(2))) __fp16 fp16x2;
typedef __attribute__((ext_vector_type(4))) float f32x4;
typedef __attribute__((ext_vector_type(16))) float f32x16;

#define B_  2
#define T_  2048
#define D_  1024
#define H_  16
#define DH_ 64
#define NSPLIT 2
#define KVSPAN (T_ / NSPLIT)

__device__ __forceinline__ f32x4 mfma16f(f16x8 a, f16x8 b, f32x4 c) {
    return __builtin_amdgcn_mfma_f32_16x16x32_f16(a, b, c, 0, 0, 0);
}
__device__ __forceinline__ f32x16 mfma32f(f16x8 a, f16x8 b, f32x16 c) {
    return __builtin_amdgcn_mfma_f32_32x32x16_f16(a, b, c, 0, 0, 0);
}
__device__ __forceinline__ void gload16(const void* g, void* l) {
    __builtin_amdgcn_global_load_lds(
        (const __attribute__((address_space(1))) uint32_t*)g,
        (__attribute__((address_space(3))) uint32_t*)l, 16, 0, 0);
}
// cross-half (lane ^ 32) max/sum via v_permlane32_swap (hazard-safe, R12).
__device__ __forceinline__ float xmax32(float x) {
    float a, b;
    asm("v_mov_b32 %0, %2\n\t"
        "v_mov_b32 %1, %2\n\t"
        "s_nop 1\n\t"
        "v_permlane32_swap_b32 %0, %1\n\t"
        "s_nop 1\n\t"
        "v_max_f32 %0, %0, %1"
        : "=&v"(a), "=&v"(b) : "v"(x));
    return a;
}
__device__ __forceinline__ float xsum32(float x) {
    float a, b;
    asm("v_mov_b32 %0, %2\n\t"
        "v_mov_b32 %1, %2\n\t"
        "s_nop 1\n\t"
        "v_permlane32_swap_b32 %0, %1\n\t"
        "s_nop 1\n\t"
        "v_add_f32 %0, %0, %1"
        : "=&v"(a), "=&v"(b) : "v"(x));
    return a;
}

// ---------------------------------------------------------------------------
// Kernel 0: pack int32 mask -> TRANSPOSED bit mask bitsT[b][word][q].
// ---------------------------------------------------------------------------
__global__ __launch_bounds__(256) void maskpack_kernel(
    const int* __restrict__ mask, uint32_t* __restrict__ bitsT)
{
    size_t e = (size_t)blockIdx.x * 256 + threadIdx.x;   // [B][T][T] linear
    unsigned long long bb = __ballot(mask[e] != 0);
    if ((threadIdx.x & 63) == 0) {
        size_t r = e >> 11;              // b*T + q
        int b = (int)(r >> 11), q = (int)(r & (T_ - 1));
        int k = (int)(e & (T_ - 1));
        int w0 = k >> 5;
        size_t base = (size_t)b * (64 * T_) + q;
        bitsT[base + (size_t)w0 * T_]       = (uint32_t)bb;
        bitsT[base + (size_t)(w0 + 1) * T_] = (uint32_t)(bb >> 32);
    }
}

// ---------------------------------------------------------------------------
// Kernel 0b: convert X fp32 -> fp16.
// ---------------------------------------------------------------------------
__global__ __launch_bounds__(256) void cvtx_kernel(
    const float* __restrict__ X, f16* __restrict__ Xh)
{
    size_t i0 = ((size_t)blockIdx.x * 256 + threadIdx.x) * 8;
    float4 a = *(const float4*)(X + i0);
    float4 b = *(const float4*)(X + i0 + 4);
    float v[8] = {a.x, a.y, a.z, a.w, b.x, b.y, b.z, b.w};
    f16x8 hh;
#pragma unroll
    for (int i = 0; i < 8; ++i) hh[i] = (f16)v[i];
    *(f16x8*)(Xh + i0) = hh;
}

// ---------------------------------------------------------------------------
// Kernel 0c: transpose weights.  W[k][n] fp32 -> WT[n][k] fp16.
// ---------------------------------------------------------------------------
__global__ __launch_bounds__(256) void wtr_kernel(
    const float* __restrict__ Wq, const float* __restrict__ Wk,
    const float* __restrict__ Wv, const float* __restrict__ Wo,
    f16* __restrict__ WqT, f16* __restrict__ WkT,
    f16* __restrict__ WvT, f16* __restrict__ WoT)
{
    __shared__ float s_t[64][65];
    const int zz = blockIdx.z;
    const float* __restrict__ W = (zz == 0) ? Wq : (zz == 1) ? Wk : (zz == 2) ? Wv : Wo;
    const int k0 = blockIdx.y * 64, n0 = blockIdx.x * 64;
    const int t = threadIdx.x;
    const int r = t >> 2, c0 = (t & 3) * 16;

#pragma unroll
    for (int j = 0; j < 4; ++j) {
        float4 v = *(const float4*)(W + (size_t)(k0 + r) * D_ + n0 + c0 + j * 4);
        s_t[r][c0 + j * 4 + 0] = v.x;
        s_t[r][c0 + j * 4 + 1] = v.y;
        s_t[r][c0 + j * 4 + 2] = v.z;
        s_t[r][c0 + j * 4 + 3] = v.w;
    }
    __syncthreads();

    const int n = t >> 2, kc = (t & 3) * 16;
    f16x8 h0, h1;
#pragma unroll
    for (int j = 0; j < 8; ++j) h0[j] = (f16)s_t[kc + j][n];
#pragma unroll
    for (int j = 0; j < 8; ++j) h1[j] = (f16)s_t[kc + 8 + j][n];
    f16* dh = (zz == 0) ? WqT : (zz == 1) ? WkT : (zz == 2) ? WvT : WoT;
    size_t o = (size_t)(n0 + n) * D_ + k0 + kc;
    *(f16x8*)(dh + o) = h0;
    *(f16x8*)(dh + o + 8) = h1;
}

// ---------------------------------------------------------------------------
// Kernel 1: 128x128 fp16 GEMM (QKV), BK=32, DOUBLE-BUFFERED single-barrier
// 2-phase (T3 minimum recipe): issue next-tile gload_lds BEFORE this tile's
// ds_read+MFMA; one __syncthreads per K-step drains both.
// z: 0=Q (fp16, *1/8)  1=K ([bh][t][dh])  2=V (BLOCKED [bh][t/32][dh][t%32])
// ---------------------------------------------------------------------------
__global__ __launch_bounds__(256) void gemm_kernel(
    const f16* __restrict__ A,
    const f16* __restrict__ BqT, const f16* __restrict__ BkT,
    const f16* __restrict__ BvT,
    const float* __restrict__ bq, const float* __restrict__ bk,
    const float* __restrict__ bv,
    f16* __restrict__ Q, f16* __restrict__ K, f16* __restrict__ Vt)
{
    __shared__ f16 sA[2][128 * 32];
    __shared__ f16 sB[2][128 * 32];

    const int z = blockIdx.z;
    const f16* __restrict__ Bm = (z == 0) ? BqT : (z == 1) ? BkT : BvT;
    const float* __restrict__ bias = (z == 0) ? bq : (z == 1) ? bk : bv;

    const int m0 = blockIdx.y * 128;
    const int n0 = blockIdx.x * 128;
    const int tid = threadIdx.x;
    const int w = tid >> 6, l = tid & 63;
    const int g = l >> 4, lr = l & 15;
    const int wm = w >> 1, wn = w & 1;

    const int srow = w * 32 + (l >> 2);
    const int skb  = (l & 3) * 8;

    f32x4 acc[4][4] = {};

#define GSTAGE(buf, kk)                                                        \
    do {                                                                       \
        _Pragma("unroll")                                                      \
        for (int i = 0; i < 2; ++i) {                                          \
            gload16(A  + (size_t)(m0 + srow + i * 16) * D_ + (kk) + skb,       \
                    &sA[buf][w * 1024 + i * 512]);                             \
            gload16(Bm + (size_t)(n0 + srow + i * 16) * D_ + (kk) + skb,       \
                    &sB[buf][w * 1024 + i * 512]);                             \
        }                                                                      \
    } while (0)

    GSTAGE(0, 0);
    __syncthreads();                       // buf0 staged (implicit vmcnt(0))
    int cur = 0;
    for (int k0 = 0; k0 < D_; k0 += 32) {
        if (k0 + 32 < D_) GSTAGE(cur ^ 1, k0 + 32);   // overlap w/ compute

        f16x8 ah[4], bh[4];
#pragma unroll
        for (int f = 0; f < 4; ++f) {
            ah[f] = *(const f16x8*)&sA[cur][(wm * 64 + f * 16 + lr) * 32 + g * 8];
            bh[f] = *(const f16x8*)&sB[cur][(wn * 64 + f * 16 + lr) * 32 + g * 8];
        }
#pragma unroll
        for (int fm = 0; fm < 4; ++fm)
#pragma unroll
            for (int fn = 0; fn < 4; ++fn)
                acc[fm][fn] = mfma16f(ah[fm], bh[fn], acc[fm][fn]);

        __syncthreads();   // drains next-buf loads + this buf's ds_reads
        cur ^= 1;
    }
#undef GSTAGE

    const float scale = (z == 0) ? 0.125f : 1.0f;
    float biasv[4];
#pragma unroll
    for (int f = 0; f < 4; ++f) biasv[f] = bias[n0 + wn * 64 + f * 16 + lr];

    if (z <= 1) {
        f16* Oq = (z == 0) ? Q : K;
#pragma unroll
        for (int fm = 0; fm < 4; ++fm)
#pragma unroll
            for (int fn = 0; fn < 4; ++fn)
#pragma unroll
                for (int j = 0; j < 4; ++j) {
                    int r = m0 + wm * 64 + fm * 16 + g * 4 + j;
                    int c = n0 + wn * 64 + fn * 16 + lr;
                    float v = (acc[fm][fn][j] + biasv[fn]) * scale;
                    int b = r >> 11, t = r & (T_ - 1);
                    int h = (c >> 6) & 15, d = c & 63;
                    Oq[((size_t)(b * H_ + h) * T_ + t) * DH_ + d] = (f16)v;
                }
    } else {
#pragma unroll
        for (int fm = 0; fm < 4; ++fm)
#pragma unroll
            for (int fn = 0; fn < 4; ++fn) {
                int r0 = m0 + wm * 64 + fm * 16 + g * 4;
                int c  = n0 + wn * 64 + fn * 16 + lr;
                int b = r0 >> 11, t0 = r0 & (T_ - 1);
                int h = (c >> 6) & 15, d = c & 63;
                union { f16 h4[4]; uint2 u; } pk;
#pragma unroll
                for (int j = 0; j < 4; ++j)
                    pk.h4[j] = (f16)(acc[fm][fn][j] + biasv[fn]);
                *(uint2*)&Vt[(size_t)(b * H_ + h) * (T_ * DH_) +
                             (size_t)(t0 >> 5) * (32 * DH_) + d * 32 + (t0 & 31)] = pk.u;
            }
    }
}

// ---------------------------------------------------------------------------
// Kernel 1b: O-projection GEMM, BM=128 x BN=64, double-buffered 2-phase.
// ---------------------------------------------------------------------------
__global__ __launch_bounds__(256) void oproj_kernel(
    const f16* __restrict__ A, const f16* __restrict__ BoT,
    const float* __restrict__ bo, float* __restrict__ outF)
{
    __shared__ f16 sA[2][128 * 32];
    __shared__ f16 sB[2][64 * 32];

    const int m0 = blockIdx.y * 128;
    const int n0 = blockIdx.x * 64;
    const int tid = threadIdx.x;
    const int w = tid >> 6, l = tid & 63;
    const int g = l >> 4, lr = l & 15;

    const int srowA = w * 32 + (l >> 2);
    const int skbA  = (l & 3) * 8;
    const int browB = w * 16 + (l >> 2);

    f32x4 acc[2][4] = {};

#define OSTAGE(buf, kk)                                                        \
    do {                                                                       \
        _Pragma("unroll")                                                      \
        for (int i = 0; i < 2; ++i)                                            \
            gload16(A + (size_t)(m0 + srowA + i * 16) * D_ + (kk) + skbA,      \
                    &sA[buf][w * 1024 + i * 512]);                             \
        gload16(BoT + (size_t)(n0 + browB) * D_ + (kk) + skbA,                 \
                &sB[buf][w * 512]);                                            \
    } while (0)

    OSTAGE(0, 0);
    __syncthreads();
    int cur = 0;
    for (int k0 = 0; k0 < D_; k0 += 32) {
        if (k0 + 32 < D_) OSTAGE(cur ^ 1, k0 + 32);

        f16x8 ah[2], bh[4];
#pragma unroll
        for (int f = 0; f < 2; ++f)
            ah[f] = *(const f16x8*)&sA[cur][(w * 32 + f * 16 + lr) * 32 + g * 8];
#pragma unroll
        for (int f = 0; f < 4; ++f)
            bh[f] = *(const f16x8*)&sB[cur][(f * 16 + lr) * 32 + g * 8];
#pragma unroll
        for (int fm = 0; fm < 2; ++fm)
#pragma unroll
            for (int fn = 0; fn < 4; ++fn)
                acc[fm][fn] = mfma16f(ah[fm], bh[fn], acc[fm][fn]);

        __syncthreads();
        cur ^= 1;
    }
#undef OSTAGE

    float biasv[4];
#pragma unroll
    for (int f = 0; f < 4; ++f) biasv[f] = bo[n0 + f * 16 + lr];
#pragma unroll
    for (int fm = 0; fm < 2; ++fm)
#pragma unroll
        for (int fn = 0; fn < 4; ++fn)
#pragma unroll
            for (int j = 0; j < 4; ++j) {
                int r = m0 + w * 32 + fm * 16 + g * 4 + j;
                int c = n0 + fn * 16 + lr;
                outF[(size_t)r * D_ + c] = acc[fm][fn][j] + biasv[fn];
            }
}

// ---------------------------------------------------------------------------
// Kernel 2: flash attention — R13 exact config (best measured: 87.4 us).
// 4-wave blocks, 128 q-rows, KVBLK=32, cooperative LDS staging (coalesced
// global_load_lds, dbuf, source-side XOR pre-swizzle), coalesced bitsT mask.
// ---------------------------------------------------------------------------
__device__ __forceinline__ void attn_tile(
    const f16x8* kh, const f16x8* vb, uint32_t mw, const f16x8* qf,
    f32x16& o0, f32x16& o1, float& m_run, float& l_run)
{
    const float L2E = 1.4426950408889634f;
    f32x16 s = {};
    __builtin_amdgcn_s_setprio(1);
    s = mfma32f(kh[0], qf[0], s);
    s = mfma32f(kh[1], qf[1], s);
    s = mfma32f(kh[2], qf[2], s);
    s = mfma32f(kh[3], qf[3], s);
    __builtin_amdgcn_s_setprio(0);

#pragma unroll
    for (int r = 0; r < 16; ++r) {
        const int bit = (r & 3) + 8 * (r >> 2);
        if (!((mw >> bit) & 1u)) s[r] = -1e30f;
    }

    float t8[8], t4[4];
#pragma unroll
    for (int i = 0; i < 8; ++i) t8[i] = fmaxf(s[i], s[i + 8]);
#pragma unroll
    for (int i = 0; i < 4; ++i) t4[i] = fmaxf(t8[i], t8[i + 4]);
    float pm = fmaxf(fmaxf(t4[0], t4[2]), fmaxf(t4[1], t4[3]));
    pm = xmax32(pm);

    if (__any(pm > m_run + 8.0f)) {        // defer-max rescale (T13)
        float mn  = fmaxf(m_run, pm);
        float fac = exp2f((m_run - mn) * L2E);
        l_run *= fac;
#pragma unroll
        for (int r = 0; r < 16; ++r) { o0[r] *= fac; o1[r] *= fac; }
        m_run = mn;
    }

    float p[16];
#pragma unroll
    for (int r = 0; r < 16; ++r) p[r] = exp2f((s[r] - m_run) * L2E);
    float a8[8], a4[4];
#pragma unroll
    for (int i = 0; i < 8; ++i) a8[i] = p[i] + p[i + 8];
#pragma unroll
    for (int i = 0; i < 4; ++i) a4[i] = a8[i] + a8[i + 4];
    float sum = (a4[0] + a4[2]) + (a4[1] + a4[3]);
    sum = xsum32(sum);
    l_run += sum;

    uint32_t wv[8];
#pragma unroll
    for (int m2 = 0; m2 < 8; ++m2) {
        union { fp16x2 h; uint32_t u; } cv;
        cv.h = __builtin_amdgcn_cvt_pkrtz(p[2 * m2], p[2 * m2 + 1]);
        wv[m2] = cv.u;
    }
    asm("v_permlane32_swap_b32 %0, %1" : "+v"(wv[0]), "+v"(wv[2]));
    asm("v_permlane32_swap_b32 %0, %1" : "+v"(wv[1]), "+v"(wv[3]));
    asm("v_permlane32_swap_b32 %0, %1" : "+v"(wv[4]), "+v"(wv[6]));
    asm("v_permlane32_swap_b32 %0, %1" : "+v"(wv[5]), "+v"(wv[7]));
    union { uint32_t u[4]; f16x8 s8; } pa1, pa2;
    pa1.u[0] = wv[0]; pa1.u[1] = wv[1]; pa1.u[2] = wv[2]; pa1.u[3] = wv[3];
    pa2.u[0] = wv[4]; pa2.u[1] = wv[5]; pa2.u[2] = wv[6]; pa2.u[3] = wv[7];

    __builtin_amdgcn_s_setprio(1);
    o0 = mfma32f(vb[0], pa1.s8, o0);
    o0 = mfma32f(vb[1], pa2.s8, o0);
    o1 = mfma32f(vb[2], pa1.s8, o1);
    o1 = mfma32f(vb[3], pa2.s8, o1);
    __builtin_amdgcn_s_setprio(0);
}

__global__ __launch_bounds__(256, 3) void attn_split_kernel(
    const f16* __restrict__ Qg, const f16* __restrict__ Kg,
    const f16* __restrict__ Vt, const uint32_t* __restrict__ bits,
    f16* __restrict__ Op0, f16* __restrict__ Op1,
    float2* __restrict__ stats)
{
    __shared__ f16 sK[2][2048];   // [32 kv rows][64 dh] fp16, 4KB per buf
    __shared__ f16 sV[2][2048];   // [64 dh rows][32 kv] fp16, 4KB per buf

    const int bx  = blockIdx.x;
    const int bh  = (bx & 7) | ((bx >> 8) << 3);
    const int mid = (bx >> 3) & 31;
    const int qb  = mid >> 1;
    const int sp  = mid & 1;
    const int b   = bh >> 4, h = bh & 15;
    const int tid = threadIdx.x;
    const int w   = tid >> 6;
    const int l   = tid & 63;
    const int qi  = l & 31;
    const int hl  = l >> 5;
    const int q   = qb * 128 + w * 32 + qi;
    const int kvbase = sp * KVSPAN;

    const size_t hoff = (size_t)(b * H_ + h) * T_ * DH_;
    const f16* Qh = Qg + hoff;
    const f16* Kh = Kg + hoff;                 // [t][dh]
    const f16* Vh = Vt + hoff;                 // blocked [t/32][dh][t%32]
    const uint32_t* mbase = bits + (size_t)b * (64 * T_) + q;

    // staging source offsets (pre-swizzled; involution on 16B chunks)
    const int krow = tid >> 3, kch = tid & 7;              // K: 32 rows x 8 chunks
    const size_t ksoff = (size_t)krow * DH_ + (size_t)((kch ^ (krow & 7)) * 8);
    const int vrow = tid >> 2, vch = tid & 3;              // V: 64 rows x 4 chunks
    const size_t vsoff = (size_t)vrow * 32 + (size_t)((vch ^ ((vrow >> 1) & 3)) * 8);

    f16x8 qf[4];
#pragma unroll
    for (int c = 0; c < 4; ++c)
        qf[c] = *(const f16x8*)&Qh[(size_t)q * DH_ + c * 16 + hl * 8];

    f32x16 o0 = {}; f32x16 o1 = {};
    float m_run = -1e30f, l_run = 0.0f;

#define STAGE(buf, kv)                                                        \
    do {                                                                      \
        gload16(Kh + (size_t)(kv) * DH_ + ksoff, &sK[buf][w * 512]);          \
        gload16(Vh + (size_t)((kv) >> 5) * 2048 + vsoff, &sV[buf][w * 512]);  \
    } while (0)

    STAGE(0, kvbase);
    __syncthreads();

    int cur = 0;
    for (int kv0 = kvbase; kv0 < kvbase + KVSPAN; kv0 += 32) {
        int nxt = kv0 + 32;
        if (nxt == kvbase + KVSPAN) nxt = kvbase;   // harmless wrap refill
        STAGE(cur ^ 1, nxt);

        uint32_t mw = mbase[(size_t)(kv0 >> 5) * T_] >> (hl * 4);

        f16x8 kh[4], vb[4];
#pragma unroll
        for (int c = 0; c < 4; ++c)
            kh[c] = *(const f16x8*)&sK[cur][qi * DH_ + (((2 * c + hl) ^ (qi & 7)) << 3)];
#pragma unroll
        for (int j = 0; j < 4; ++j) {
            int row = (j >> 1) * 32 + qi;
            int ch  = ((j & 1) * 2 + hl) ^ ((qi >> 1) & 3);
            vb[j] = *(const f16x8*)&sV[cur][row * 32 + (ch << 3)];
        }

        attn_tile(kh, vb, mw, qf, o0, o1, m_run, l_run);
        __syncthreads();   // drains this tile's prefetch; syncs buffer swap
        cur ^= 1;
    }
#undef STAGE

    // epilogue: normalized partial O -> Op[sp], stats (m,l) -> stats[sp]
    float inv = 1.0f / l_run;
    float ov[32];
#pragma unroll
    for (int r = 0; r < 16; ++r) { ov[r] = o0[r]; ov[16 + r] = o1[r]; }
    f16* Op = (sp == 0) ? Op0 : Op1;
    f16* prow = Op + ((size_t)bh * T_ + q) * DH_;
#pragma unroll
    for (int dt = 0; dt < 2; ++dt)
#pragma unroll
        for (int g2 = 0; g2 < 4; ++g2) {
            union { f16 h4[4]; uint2 u; } pk;
#pragma unroll
            for (int j = 0; j < 4; ++j)
                pk.h4[j] = (f16)(ov[dt * 16 + 4 * g2 + j] * inv);
            *(uint2*)(prow + dt * 32 + 8 * g2 + 4 * hl) = pk.u;
        }
    if (hl == 0)
        stats[(size_t)sp * (32 * T_) + (size_t)bh * T_ + q] =
            make_float2(m_run, l_run);
}

// ---------------------------------------------------------------------------
// Kernel 2b: combine the two KV-split partials -> comb (fp16 [B,T,D]).
// ---------------------------------------------------------------------------
__global__ __launch_bounds__(256) void combine_kernel(
    const f16* __restrict__ Op0, const f16* __restrict__ Op1,
    const float2* __restrict__ stats, f16* __restrict__ comb)
{
    const float L2E = 1.4426950408889634f;
    const int row = blockIdx.x * 32 + (threadIdx.x >> 3);   // [0, 32*T_)
    const int dh0 = (threadIdx.x & 7) * 8;
    const int bh = row >> 11, q = row & (T_ - 1);
    const int b = bh >> 4, h = bh & 15;

    float2 s0 = stats[row];
    float2 s1 = stats[32 * T_ + row];
    float m = fmaxf(s0.x, s1.x);
    float w0 = s0.y * exp2f((s0.x - m) * L2E);
    float w1 = s1.y * exp2f((s1.x - m) * L2E);
    float rs = 1.0f / (w0 + w1);
    float a0 = w0 * rs, a1 = w1 * rs;

    f16x8 v0 = *(const f16x8*)(Op0 + (size_t)row * DH_ + dh0);
    f16x8 v1 = *(const f16x8*)(Op1 + (size_t)row * DH_ + dh0);
    f16x8 ou;
#pragma unroll
    for (int i = 0; i < 8; ++i)
        ou[i] = (f16)(a0 * (float)v0[i] + a1 * (float)v1[i]);
    *(f16x8*)(comb + ((size_t)(b * T_ + q)) * D_ + h * DH_ + dh0) = ou;
}

// ---------------------------------------------------------------------------
extern "C" void kernel_launch(void* const* d_in, const int* in_sizes, int n_in,
                              void* d_out, int out_size, void* d_ws, size_t ws_size,
                              hipStream_t stream)
{
    const float* X    = (const float*)d_in[0];
    const int*   mask = (const int*)d_in[1];
    const float* Wq   = (const float*)d_in[2];
    const float* bq   = (const float*)d_in[3];
    const float* Wk   = (const float*)d_in[4];
    const float* bk   = (const float*)d_in[5];
    const float* Wv   = (const float*)d_in[6];
    const float* bv   = (const float*)d_in[7];
    const float* Wo   = (const float*)d_in[8];
    const float* bo   = (const float*)d_in[9];
    float* out = (float*)d_out;

    const size_t SEG  = (size_t)B_ * T_ * D_;   // 4,194,304 elems (8 MiB fp16)
    const size_t WSEG = (size_t)D_ * D_;        // 2 MiB fp16
    f16* wsp = (f16*)d_ws;
    f16* Q    = wsp + 0 * SEG;
    f16* K    = wsp + 1 * SEG;
    f16* Xh   = wsp + 2 * SEG;     // comb aliases Xh after QKV GEMM
    f16* Op0  = wsp + 3 * SEG;
    f16* WqT  = wsp + 4 * SEG;
    f16* WkT  = WqT + 1 * WSEG;
    f16* WvT  = WqT + 2 * WSEG;
    f16* WoT  = WqT + 3 * WSEG;
    f16* Op1  = wsp + 5 * SEG;     // ws total: 48 MiB
    f16* comb = Xh;
    // d_out scratch: Vt (8 MiB) + bitsT (1 MiB) + stats (1 MiB); oproj
    // overwrites all of d_out.
    f16* Vt = (f16*)d_out;
    uint32_t* bits = (uint32_t*)((char*)d_out + (8u << 20));
    float2* stats  = (float2*)((char*)d_out + (9u << 20));

    dim3 blk(256);
    maskpack_kernel<<<dim3((B_ * T_ * T_) / 256), blk, 0, stream>>>(mask, bits);
    cvtx_kernel<<<dim3((B_ * T_ * D_) / 2048), blk, 0, stream>>>(X, Xh);
    wtr_kernel<<<dim3(16, 16, 4), blk, 0, stream>>>(
        Wq, Wk, Wv, Wo, WqT, WkT, WvT, WoT);
    gemm_kernel<<<dim3(D_ / 128, (B_ * T_) / 128, 3), blk, 0, stream>>>(
        Xh, WqT, WkT, WvT, bq, bk, bv, Q, K, Vt);
    attn_split_kernel<<<dim3(B_ * H_ * (T_ / 128) * NSPLIT), blk, 0, stream>>>(
        Q, K, Vt, bits, Op0, Op1, stats);
    combine_kernel<<<dim3((32 * T_) / 32), blk, 0, stream>>>(
        Op0, Op1, stats, comb);
    oproj_kernel<<<dim3(D_ / 64, (B_ * T_) / 128), blk, 0, stream>>>(
        comb, WoT, bo, out);
}

// Round 18
// 159.126 us; speedup vs baseline: 1.1605x; 1.1605x over previous
//
#include <hip/hip_runtime.h>
#include <hip/hip_bf16.h>
#include <stdint.h>

typedef _Float16 f16;
typedef __attribute__((ext_vector_type(8))) _Float16 f16x8;
typedef __attribute__((ext_vector_type(2))) __fp16 fp16x2;
typedef __attribute__((ext_vector_type(4))) float f32x4;
typedef __attribute__((ext_vector_type(16))) float f32x16;

#define B_  2
#define T_  2048
#define D_  1024
#define H_  16
#define DH_ 64
#define NSPLIT 2
#define KVSPAN (T_ / NSPLIT)

__device__ __forceinline__ f32x4 mfma16f(f16x8 a, f16x8 b, f32x4 c) {
    return __builtin_amdgcn_mfma_f32_16x16x32_f16(a, b, c, 0, 0, 0);
}
__device__ __forceinline__ f32x16 mfma32f(f16x8 a, f16x8 b, f32x16 c) {
    return __builtin_amdgcn_mfma_f32_32x32x16_f16(a, b, c, 0, 0, 0);
}
__device__ __forceinline__ void gload16(const void* g, void* l) {
    __builtin_amdgcn_global_load_lds(
        (const __attribute__((address_space(1))) uint32_t*)g,
        (__attribute__((address_space(3))) uint32_t*)l, 16, 0, 0);
}
// cross-half (lane ^ 32) max/sum via v_permlane32_swap (hazard-safe, R12).
__device__ __forceinline__ float xmax32(float x) {
    float a, b;
    asm("v_mov_b32 %0, %2\n\t"
        "v_mov_b32 %1, %2\n\t"
        "s_nop 1\n\t"
        "v_permlane32_swap_b32 %0, %1\n\t"
        "s_nop 1\n\t"
        "v_max_f32 %0, %0, %1"
        : "=&v"(a), "=&v"(b) : "v"(x));
    return a;
}
__device__ __forceinline__ float xsum32(float x) {
    float a, b;
    asm("v_mov_b32 %0, %2\n\t"
        "v_mov_b32 %1, %2\n\t"
        "s_nop 1\n\t"
        "v_permlane32_swap_b32 %0, %1\n\t"
        "s_nop 1\n\t"
        "v_add_f32 %0, %0, %1"
        : "=&v"(a), "=&v"(b) : "v"(x));
    return a;
}

// ---------------------------------------------------------------------------
// Kernel 0: pack int32 mask -> TRANSPOSED bit mask bitsT[b][word][q].
// ---------------------------------------------------------------------------
__global__ __launch_bounds__(256) void maskpack_kernel(
    const int* __restrict__ mask, uint32_t* __restrict__ bitsT)
{
    size_t e = (size_t)blockIdx.x * 256 + threadIdx.x;   // [B][T][T] linear
    unsigned long long bb = __ballot(mask[e] != 0);
    if ((threadIdx.x & 63) == 0) {
        size_t r = e >> 11;              // b*T + q
        int b = (int)(r >> 11), q = (int)(r & (T_ - 1));
        int k = (int)(e & (T_ - 1));
        int w0 = k >> 5;
        size_t base = (size_t)b * (64 * T_) + q;
        bitsT[base + (size_t)w0 * T_]       = (uint32_t)bb;
        bitsT[base + (size_t)(w0 + 1) * T_] = (uint32_t)(bb >> 32);
    }
}

// ---------------------------------------------------------------------------
// Kernel 0b: convert X fp32 -> fp16.
// ---------------------------------------------------------------------------
__global__ __launch_bounds__(256) void cvtx_kernel(
    const float* __restrict__ X, f16* __restrict__ Xh)
{
    size_t i0 = ((size_t)blockIdx.x * 256 + threadIdx.x) * 8;
    float4 a = *(const float4*)(X + i0);
    float4 b = *(const float4*)(X + i0 + 4);
    float v[8] = {a.x, a.y, a.z, a.w, b.x, b.y, b.z, b.w};
    f16x8 hh;
#pragma unroll
    for (int i = 0; i < 8; ++i) hh[i] = (f16)v[i];
    *(f16x8*)(Xh + i0) = hh;
}

// ---------------------------------------------------------------------------
// Kernel 0c: transpose weights.  W[k][n] fp32 -> WT[n][k] fp16.
// ---------------------------------------------------------------------------
__global__ __launch_bounds__(256) void wtr_kernel(
    const float* __restrict__ Wq, const float* __restrict__ Wk,
    const float* __restrict__ Wv, const float* __restrict__ Wo,
    f16* __restrict__ WqT, f16* __restrict__ WkT,
    f16* __restrict__ WvT, f16* __restrict__ WoT)
{
    __shared__ float s_t[64][65];
    const int zz = blockIdx.z;
    const float* __restrict__ W = (zz == 0) ? Wq : (zz == 1) ? Wk : (zz == 2) ? Wv : Wo;
    const int k0 = blockIdx.y * 64, n0 = blockIdx.x * 64;
    const int t = threadIdx.x;
    const int r = t >> 2, c0 = (t & 3) * 16;

#pragma unroll
    for (int j = 0; j < 4; ++j) {
        float4 v = *(const float4*)(W + (size_t)(k0 + r) * D_ + n0 + c0 + j * 4);
        s_t[r][c0 + j * 4 + 0] = v.x;
        s_t[r][c0 + j * 4 + 1] = v.y;
        s_t[r][c0 + j * 4 + 2] = v.z;
        s_t[r][c0 + j * 4 + 3] = v.w;
    }
    __syncthreads();

    const int n = t >> 2, kc = (t & 3) * 16;
    f16x8 h0, h1;
#pragma unroll
    for (int j = 0; j < 8; ++j) h0[j] = (f16)s_t[kc + j][n];
#pragma unroll
    for (int j = 0; j < 8; ++j) h1[j] = (f16)s_t[kc + 8 + j][n];
    f16* dh = (zz == 0) ? WqT : (zz == 1) ? WkT : (zz == 2) ? WvT : WoT;
    size_t o = (size_t)(n0 + n) * D_ + k0 + kc;
    *(f16x8*)(dh + o) = h0;
    *(f16x8*)(dh + o + 8) = h1;
}

// ---------------------------------------------------------------------------
// Kernel 1: 128x128 fp16 GEMM (QKV), BK=32, single-buffer 2-barrier
// (R15-proven; dbuf variant regressed in R17).
// z: 0=Q (fp16, *1/8)  1=K ([bh][t][dh])  2=V (BLOCKED [bh][t/32][dh][t%32])
// ---------------------------------------------------------------------------
__global__ __launch_bounds__(256) void gemm_kernel(
    const f16* __restrict__ A,
    const f16* __restrict__ BqT, const f16* __restrict__ BkT,
    const f16* __restrict__ BvT,
    const float* __restrict__ bq, const float* __restrict__ bk,
    const float* __restrict__ bv,
    f16* __restrict__ Q, f16* __restrict__ K, f16* __restrict__ Vt)
{
    __shared__ f16 sA[128 * 32];
    __shared__ f16 sB[128 * 32];

    const int z = blockIdx.z;
    const f16* __restrict__ Bm = (z == 0) ? BqT : (z == 1) ? BkT : BvT;
    const float* __restrict__ bias = (z == 0) ? bq : (z == 1) ? bk : bv;

    const int m0 = blockIdx.y * 128;
    const int n0 = blockIdx.x * 128;
    const int tid = threadIdx.x;
    const int w = tid >> 6, l = tid & 63;
    const int g = l >> 4, lr = l & 15;
    const int wm = w >> 1, wn = w & 1;

    const int srow = w * 32 + (l >> 2);
    const int skb  = (l & 3) * 8;

    f32x4 acc[4][4] = {};

    for (int k0 = 0; k0 < D_; k0 += 32) {
        __syncthreads();
#pragma unroll
        for (int i = 0; i < 2; ++i) {
            gload16(A  + (size_t)(m0 + srow + i * 16) * D_ + k0 + skb,
                    &sA[w * 1024 + i * 512]);
            gload16(Bm + (size_t)(n0 + srow + i * 16) * D_ + k0 + skb,
                    &sB[w * 1024 + i * 512]);
        }
        __syncthreads();

        f16x8 ah[4], bh[4];
#pragma unroll
        for (int f = 0; f < 4; ++f) {
            ah[f] = *(const f16x8*)&sA[(wm * 64 + f * 16 + lr) * 32 + g * 8];
            bh[f] = *(const f16x8*)&sB[(wn * 64 + f * 16 + lr) * 32 + g * 8];
        }
#pragma unroll
        for (int fm = 0; fm < 4; ++fm)
#pragma unroll
            for (int fn = 0; fn < 4; ++fn)
                acc[fm][fn] = mfma16f(ah[fm], bh[fn], acc[fm][fn]);
    }

    const float scale = (z == 0) ? 0.125f : 1.0f;
    float biasv[4];
#pragma unroll
    for (int f = 0; f < 4; ++f) biasv[f] = bias[n0 + wn * 64 + f * 16 + lr];

    if (z <= 1) {
        f16* Oq = (z == 0) ? Q : K;
#pragma unroll
        for (int fm = 0; fm < 4; ++fm)
#pragma unroll
            for (int fn = 0; fn < 4; ++fn)
#pragma unroll
                for (int j = 0; j < 4; ++j) {
                    int r = m0 + wm * 64 + fm * 16 + g * 4 + j;
                    int c = n0 + wn * 64 + fn * 16 + lr;
                    float v = (acc[fm][fn][j] + biasv[fn]) * scale;
                    int b = r >> 11, t = r & (T_ - 1);
                    int h = (c >> 6) & 15, d = c & 63;
                    Oq[((size_t)(b * H_ + h) * T_ + t) * DH_ + d] = (f16)v;
                }
    } else {
#pragma unroll
        for (int fm = 0; fm < 4; ++fm)
#pragma unroll
            for (int fn = 0; fn < 4; ++fn) {
                int r0 = m0 + wm * 64 + fm * 16 + g * 4;
                int c  = n0 + wn * 64 + fn * 16 + lr;
                int b = r0 >> 11, t0 = r0 & (T_ - 1);
                int h = (c >> 6) & 15, d = c & 63;
                union { f16 h4[4]; uint2 u; } pk;
#pragma unroll
                for (int j = 0; j < 4; ++j)
                    pk.h4[j] = (f16)(acc[fm][fn][j] + biasv[fn]);
                *(uint2*)&Vt[(size_t)(b * H_ + h) * (T_ * DH_) +
                             (size_t)(t0 >> 5) * (32 * DH_) + d * 32 + (t0 & 31)] = pk.u;
            }
    }
}

// ---------------------------------------------------------------------------
// Kernel 1b: O-projection GEMM, BM=128 x BN=64 (single-buffer, R15-proven).
// ---------------------------------------------------------------------------
__global__ __launch_bounds__(256) void oproj_kernel(
    const f16* __restrict__ A, const f16* __restrict__ BoT,
    const float* __restrict__ bo, float* __restrict__ outF)
{
    __shared__ f16 sA[128 * 32];
    __shared__ f16 sB[64 * 32];

    const int m0 = blockIdx.y * 128;
    const int n0 = blockIdx.x * 64;
    const int tid = threadIdx.x;
    const int w = tid >> 6, l = tid & 63;
    const int g = l >> 4, lr = l & 15;

    const int srowA = w * 32 + (l >> 2);
    const int skbA  = (l & 3) * 8;
    const int browB = w * 16 + (l >> 2);

    f32x4 acc[2][4] = {};

    for (int k0 = 0; k0 < D_; k0 += 32) {
        __syncthreads();
#pragma unroll
        for (int i = 0; i < 2; ++i)
            gload16(A + (size_t)(m0 + srowA + i * 16) * D_ + k0 + skbA,
                    &sA[w * 1024 + i * 512]);
        gload16(BoT + (size_t)(n0 + browB) * D_ + k0 + skbA,
                &sB[w * 512]);
        __syncthreads();

        f16x8 ah[2], bh[4];
#pragma unroll
        for (int f = 0; f < 2; ++f)
            ah[f] = *(const f16x8*)&sA[(w * 32 + f * 16 + lr) * 32 + g * 8];
#pragma unroll
        for (int f = 0; f < 4; ++f)
            bh[f] = *(const f16x8*)&sB[(f * 16 + lr) * 32 + g * 8];
#pragma unroll
        for (int fm = 0; fm < 2; ++fm)
#pragma unroll
            for (int fn = 0; fn < 4; ++fn)
                acc[fm][fn] = mfma16f(ah[fm], bh[fn], acc[fm][fn]);
    }

    float biasv[4];
#pragma unroll
    for (int f = 0; f < 4; ++f) biasv[f] = bo[n0 + f * 16 + lr];
#pragma unroll
    for (int fm = 0; fm < 2; ++fm)
#pragma unroll
        for (int fn = 0; fn < 4; ++fn)
#pragma unroll
            for (int j = 0; j < 4; ++j) {
                int r = m0 + w * 32 + fm * 16 + g * 4 + j;
                int c = n0 + fn * 16 + lr;
                outF[(size_t)r * D_ + c] = acc[fm][fn][j] + biasv[fn];
            }
}

// ---------------------------------------------------------------------------
// Kernel 2: flash attention — R13 exact config (best measured: 87.4 us).
// 4-wave blocks, 128 q-rows, KVBLK=32, cooperative LDS staging (coalesced
// global_load_lds, dbuf, source-side XOR pre-swizzle), coalesced bitsT mask.
// ---------------------------------------------------------------------------
__device__ __forceinline__ void attn_tile(
    const f16x8* kh, const f16x8* vb, uint32_t mw, const f16x8* qf,
    f32x16& o0, f32x16& o1, float& m_run, float& l_run)
{
    const float L2E = 1.4426950408889634f;
    f32x16 s = {};
    __builtin_amdgcn_s_setprio(1);
    s = mfma32f(kh[0], qf[0], s);
    s = mfma32f(kh[1], qf[1], s);
    s = mfma32f(kh[2], qf[2], s);
    s = mfma32f(kh[3], qf[3], s);
    __builtin_amdgcn_s_setprio(0);

#pragma unroll
    for (int r = 0; r < 16; ++r) {
        const int bit = (r & 3) + 8 * (r >> 2);
        if (!((mw >> bit) & 1u)) s[r] = -1e30f;
    }

    float t8[8], t4[4];
#pragma unroll
    for (int i = 0; i < 8; ++i) t8[i] = fmaxf(s[i], s[i + 8]);
#pragma unroll
    for (int i = 0; i < 4; ++i) t4[i] = fmaxf(t8[i], t8[i + 4]);
    float pm = fmaxf(fmaxf(t4[0], t4[2]), fmaxf(t4[1], t4[3]));
    pm = xmax32(pm);

    if (__any(pm > m_run + 8.0f)) {        // defer-max rescale (T13)
        float mn  = fmaxf(m_run, pm);
        float fac = exp2f((m_run - mn) * L2E);
        l_run *= fac;
#pragma unroll
        for (int r = 0; r < 16; ++r) { o0[r] *= fac; o1[r] *= fac; }
        m_run = mn;
    }

    float p[16];
#pragma unroll
    for (int r = 0; r < 16; ++r) p[r] = exp2f((s[r] - m_run) * L2E);
    float a8[8], a4[4];
#pragma unroll
    for (int i = 0; i < 8; ++i) a8[i] = p[i] + p[i + 8];
#pragma unroll
    for (int i = 0; i < 4; ++i) a4[i] = a8[i] + a8[i + 4];
    float sum = (a4[0] + a4[2]) + (a4[1] + a4[3]);
    sum = xsum32(sum);
    l_run += sum;

    uint32_t wv[8];
#pragma unroll
    for (int m2 = 0; m2 < 8; ++m2) {
        union { fp16x2 h; uint32_t u; } cv;
        cv.h = __builtin_amdgcn_cvt_pkrtz(p[2 * m2], p[2 * m2 + 1]);
        wv[m2] = cv.u;
    }
    asm("v_permlane32_swap_b32 %0, %1" : "+v"(wv[0]), "+v"(wv[2]));
    asm("v_permlane32_swap_b32 %0, %1" : "+v"(wv[1]), "+v"(wv[3]));
    asm("v_permlane32_swap_b32 %0, %1" : "+v"(wv[4]), "+v"(wv[6]));
    asm("v_permlane32_swap_b32 %0, %1" : "+v"(wv[5]), "+v"(wv[7]));
    union { uint32_t u[4]; f16x8 s8; } pa1, pa2;
    pa1.u[0] = wv[0]; pa1.u[1] = wv[1]; pa1.u[2] = wv[2]; pa1.u[3] = wv[3];
    pa2.u[0] = wv[4]; pa2.u[1] = wv[5]; pa2.u[2] = wv[6]; pa2.u[3] = wv[7];

    __builtin_amdgcn_s_setprio(1);
    o0 = mfma32f(vb[0], pa1.s8, o0);
    o0 = mfma32f(vb[1], pa2.s8, o0);
    o1 = mfma32f(vb[2], pa1.s8, o1);
    o1 = mfma32f(vb[3], pa2.s8, o1);
    __builtin_amdgcn_s_setprio(0);
}

__global__ __launch_bounds__(256, 3) void attn_split_kernel(
    const f16* __restrict__ Qg, const f16* __restrict__ Kg,
    const f16* __restrict__ Vt, const uint32_t* __restrict__ bits,
    f16* __restrict__ Op0, f16* __restrict__ Op1,
    float2* __restrict__ stats)
{
    __shared__ f16 sK[2][2048];   // [32 kv rows][64 dh] fp16, 4KB per buf
    __shared__ f16 sV[2][2048];   // [64 dh rows][32 kv] fp16, 4KB per buf

    const int bx  = blockIdx.x;
    const int bh  = (bx & 7) | ((bx >> 8) << 3);
    const int mid = (bx >> 3) & 31;
    const int qb  = mid >> 1;
    const int sp  = mid & 1;
    const int b   = bh >> 4, h = bh & 15;
    const int tid = threadIdx.x;
    const int w   = tid >> 6;
    const int l   = tid & 63;
    const int qi  = l & 31;
    const int hl  = l >> 5;
    const int q   = qb * 128 + w * 32 + qi;
    const int kvbase = sp * KVSPAN;

    const size_t hoff = (size_t)(b * H_ + h) * T_ * DH_;
    const f16* Qh = Qg + hoff;
    const f16* Kh = Kg + hoff;                 // [t][dh]
    const f16* Vh = Vt + hoff;                 // blocked [t/32][dh][t%32]
    const uint32_t* mbase = bits + (size_t)b * (64 * T_) + q;

    // staging source offsets (pre-swizzled; involution on 16B chunks)
    const int krow = tid >> 3, kch = tid & 7;              // K: 32 rows x 8 chunks
    const size_t ksoff = (size_t)krow * DH_ + (size_t)((kch ^ (krow & 7)) * 8);
    const int vrow = tid >> 2, vch = tid & 3;              // V: 64 rows x 4 chunks
    const size_t vsoff = (size_t)vrow * 32 + (size_t)((vch ^ ((vrow >> 1) & 3)) * 8);

    f16x8 qf[4];
#pragma unroll
    for (int c = 0; c < 4; ++c)
        qf[c] = *(const f16x8*)&Qh[(size_t)q * DH_ + c * 16 + hl * 8];

    f32x16 o0 = {}; f32x16 o1 = {};
    float m_run = -1e30f, l_run = 0.0f;

#define STAGE(buf, kv)                                                        \
    do {                                                                      \
        gload16(Kh + (size_t)(kv) * DH_ + ksoff, &sK[buf][w * 512]);          \
        gload16(Vh + (size_t)((kv) >> 5) * 2048 + vsoff, &sV[buf][w * 512]);  \
    } while (0)

    STAGE(0, kvbase);
    __syncthreads();

    int cur = 0;
    for (int kv0 = kvbase; kv0 < kvbase + KVSPAN; kv0 += 32) {
        int nxt = kv0 + 32;
        if (nxt == kvbase + KVSPAN) nxt = kvbase;   // harmless wrap refill
        STAGE(cur ^ 1, nxt);

        uint32_t mw = mbase[(size_t)(kv0 >> 5) * T_] >> (hl * 4);

        f16x8 kh[4], vb[4];
#pragma unroll
        for (int c = 0; c < 4; ++c)
            kh[c] = *(const f16x8*)&sK[cur][qi * DH_ + (((2 * c + hl) ^ (qi & 7)) << 3)];
#pragma unroll
        for (int j = 0; j < 4; ++j) {
            int row = (j >> 1) * 32 + qi;
            int ch  = ((j & 1) * 2 + hl) ^ ((qi >> 1) & 3);
            vb[j] = *(const f16x8*)&sV[cur][row * 32 + (ch << 3)];
        }

        attn_tile(kh, vb, mw, qf, o0, o1, m_run, l_run);
        __syncthreads();   // drains this tile's prefetch; syncs buffer swap
        cur ^= 1;
    }
#undef STAGE

    // epilogue: normalized partial O -> Op[sp], stats (m,l) -> stats[sp]
    float inv = 1.0f / l_run;
    float ov[32];
#pragma unroll
    for (int r = 0; r < 16; ++r) { ov[r] = o0[r]; ov[16 + r] = o1[r]; }
    f16* Op = (sp == 0) ? Op0 : Op1;
    f16* prow = Op + ((size_t)bh * T_ + q) * DH_;
#pragma unroll
    for (int dt = 0; dt < 2; ++dt)
#pragma unroll
        for (int g2 = 0; g2 < 4; ++g2) {
            union { f16 h4[4]; uint2 u; } pk;
#pragma unroll
            for (int j = 0; j < 4; ++j)
                pk.h4[j] = (f16)(ov[dt * 16 + 4 * g2 + j] * inv);
            *(uint2*)(prow + dt * 32 + 8 * g2 + 4 * hl) = pk.u;
        }
    if (hl == 0)
        stats[(size_t)sp * (32 * T_) + (size_t)bh * T_ + q] =
            make_float2(m_run, l_run);
}

// ---------------------------------------------------------------------------
// Kernel 2b: combine the two KV-split partials -> comb (fp16 [B,T,D]).
// ---------------------------------------------------------------------------
__global__ __launch_bounds__(256) void combine_kernel(
    const f16* __restrict__ Op0, const f16* __restrict__ Op1,
    const float2* __restrict__ stats, f16* __restrict__ comb)
{
    const float L2E = 1.4426950408889634f;
    const int row = blockIdx.x * 32 + (threadIdx.x >> 3);   // [0, 32*T_)
    const int dh0 = (threadIdx.x & 7) * 8;
    const int bh = row >> 11, q = row & (T_ - 1);
    const int b = bh >> 4, h = bh & 15;

    float2 s0 = stats[row];
    float2 s1 = stats[32 * T_ + row];
    float m = fmaxf(s0.x, s1.x);
    float w0 = s0.y * exp2f((s0.x - m) * L2E);
    float w1 = s1.y * exp2f((s1.x - m) * L2E);
    float rs = 1.0f / (w0 + w1);
    float a0 = w0 * rs, a1 = w1 * rs;

    f16x8 v0 = *(const f16x8*)(Op0 + (size_t)row * DH_ + dh0);
    f16x8 v1 = *(const f16x8*)(Op1 + (size_t)row * DH_ + dh0);
    f16x8 ou;
#pragma unroll
    for (int i = 0; i < 8; ++i)
        ou[i] = (f16)(a0 * (float)v0[i] + a1 * (float)v1[i]);
    *(f16x8*)(comb + ((size_t)(b * T_ + q)) * D_ + h * DH_ + dh0) = ou;
}

// ---------------------------------------------------------------------------
extern "C" void kernel_launch(void* const* d_in, const int* in_sizes, int n_in,
                              void* d_out, int out_size, void* d_ws, size_t ws_size,
                              hipStream_t stream)
{
    const float* X    = (const float*)d_in[0];
    const int*   mask = (const int*)d_in[1];
    const float* Wq   = (const float*)d_in[2];
    const float* bq   = (const float*)d_in[3];
    const float* Wk   = (const float*)d_in[4];
    const float* bk   = (const float*)d_in[5];
    const float* Wv   = (const float*)d_in[6];
    const float* bv   = (const float*)d_in[7];
    const float* Wo   = (const float*)d_in[8];
    const float* bo   = (const float*)d_in[9];
    float* out = (float*)d_out;

    const size_t SEG  = (size_t)B_ * T_ * D_;   // 4,194,304 elems (8 MiB fp16)
    const size_t WSEG = (size_t)D_ * D_;        // 2 MiB fp16
    f16* wsp = (f16*)d_ws;
    f16* Q    = wsp + 0 * SEG;
    f16* K    = wsp + 1 * SEG;
    f16* Xh   = wsp + 2 * SEG;     // comb aliases Xh after QKV GEMM
    f16* Op0  = wsp + 3 * SEG;
    f16* WqT  = wsp + 4 * SEG;
    f16* WkT  = WqT + 1 * WSEG;
    f16* WvT  = WqT + 2 * WSEG;
    f16* WoT  = WqT + 3 * WSEG;
    f16* Op1  = wsp + 5 * SEG;     // ws total: 48 MiB
    f16* comb = Xh;
    // d_out scratch: Vt (8 MiB) + bitsT (1 MiB) + stats (1 MiB); oproj
    // overwrites all of d_out.
    f16* Vt = (f16*)d_out;
    uint32_t* bits = (uint32_t*)((char*)d_out + (8u << 20));
    float2* stats  = (float2*)((char*)d_out + (9u << 20));

    dim3 blk(256);
    maskpack_kernel<<<dim3((B_ * T_ * T_) / 256), blk, 0, stream>>>(mask, bits);
    cvtx_kernel<<<dim3((B_ * T_ * D_) / 2048), blk, 0, stream>>>(X, Xh);
    wtr_kernel<<<dim3(16, 16, 4), blk, 0, stream>>>(
        Wq, Wk, Wv, Wo, WqT, WkT, WvT, WoT);
    gemm_kernel<<<dim3(D_ / 128, (B_ * T_) / 128, 3), blk, 0, stream>>>(
        Xh, WqT, WkT, WvT, bq, bk, bv, Q, K, Vt);
    attn_split_kernel<<<dim3(B_ * H_ * (T_ / 128) * NSPLIT), blk, 0, stream>>>(
        Q, K, Vt, bits, Op0, Op1, stats);
    combine_kernel<<<dim3((32 * T_) / 32), blk, 0, stream>>>(
        Op0, Op1, stats, comb);
    oproj_kernel<<<dim3(D_ / 64, (B_ * T_) / 128), blk, 0, stream>>>(
        comb, WoT, bo, out);
}